// Round 6
// baseline (91.904 us; speedup 1.0000x reference)
//
#include <hip/hip_runtime.h>
#include <hip/hip_bf16.h>
#include <cstdint>
#include <cstddef>

typedef __attribute__((ext_vector_type(8))) short bf16x8;
typedef __attribute__((ext_vector_type(4))) float f32x4;

#define BATCH 8
#define NTOK 8192
#define LDIM 512
#define DDIM 128
#define NQ 16

static __device__ __forceinline__ short f2bf(float f) {
  uint32_t u = __float_as_uint(f);
  uint32_t r = u + 0x7fffu + ((u >> 16) & 1u); // RNE
  return (short)(r >> 16);
}

static __device__ __forceinline__ bf16x8 cvt8(float4 a, float4 b) {
  bf16x8 o;
  o[0] = f2bf(a.x); o[1] = f2bf(a.y); o[2] = f2bf(a.z); o[3] = f2bf(a.w);
  o[4] = f2bf(b.x); o[5] = f2bf(b.y); o[6] = f2bf(b.z); o[7] = f2bf(b.w);
  return o;
}

// pad-mask accessor robust to bool-ABI (byteFlag=1: 1B/elem, 0: int32/elem)
static __device__ __forceinline__ bool is_pad(const void* pad, int byteFlag, int j) {
  return byteFlag ? (((const unsigned char*)pad)[j] != 0)
                  : (((const int*)pad)[j] != 0);
}

// ---------------- k0: repack W1 -> MFMA B-frag order bf16; block 0 detects bool ABI ----------
// wfrag[(c*8 + t)*64 + lane][i] = bf16( W1[c*32 + (lane>>4)*8 + i][t*16 + (lane&15)] )
__global__ __launch_bounds__(256) void k0_wfrag(const float* __restrict__ W1,
                                                short* __restrict__ wfrag,
                                                const unsigned int* __restrict__ pad_raw,
                                                int* __restrict__ flag) {
  int tid = blockIdx.x * blockDim.x + threadIdx.x;
  if (tid < 16 * 8 * 64) {
    int l = tid & 63;
    int t = (tid >> 6) & 7;
    int c = tid >> 9;
    int kbase = c * 32 + (l >> 4) * 8;
    int col = t * 16 + (l & 15);
    bf16x8 frag;
#pragma unroll
    for (int i = 0; i < 8; ++i) frag[i] = f2bf(W1[(size_t)(kbase + i) * DDIM + col]);
    ((bf16x8*)wfrag)[tid] = frag;
  }
  if (blockIdx.x == 0) {
    int any_gt1 = 0;
    for (int i = threadIdx.x; i < 16384; i += 256)
      if (pad_raw[i] > 1u) any_gt1 = 1;
    unsigned long long m = __ballot(any_gt1);
    __shared__ int s[4];
    if ((threadIdx.x & 63) == 0) s[threadIdx.x >> 6] = (m != 0ull) ? 1 : 0;
    __syncthreads();
    if (threadIdx.x == 0) flag[0] = (s[0] | s[1] | s[2] | s[3]);
  }
}

// ---------------- k1: scores + FUSED pooling (no softmax max needed: |A| <= ||W2||_1 ~ 9) ----
// 512 thr (8 waves) x 16 rows/wave = 128 rows/block; grid 512.
// Phase 1: MFMA GEMM (W1 staged in 4x32KB LDS quarters).
// Phase 2: weights wt=exp(A) per row; wave-0 groups rows by q (deterministic ballot sort);
//          each wave owns 64 cols, accumulates per-q sums from L2-hot x; writes partials.
__global__ __launch_bounds__(512, 6) void k1_fused(const float* __restrict__ x,
                                                   const short* __restrict__ wfrag,
                                                   const float* __restrict__ W2,
                                                   const int* __restrict__ ids,
                                                   const void* __restrict__ pad,
                                                   const int* __restrict__ flag,
                                                   float* __restrict__ partial,
                                                   float* __restrict__ wsum_p) {
  __shared__ short ldsw[16384]; // 32 KB: one quarter of wfrag (4 K-chunks)
  __shared__ float wt_l[128];
  __shared__ int qq_l[128];
  __shared__ int idx_l[128];
  __shared__ int off_l[17];
  const int tid = threadIdx.x, wave = tid >> 6, lane = tid & 63;
  const int rowBase = blockIdx.x * 128 + wave * 16;
  const float* xp = x + (size_t)(rowBase + (lane & 15)) * LDIM + ((lane >> 4) * 8);

// stage 32KB quarter qd of wfrag into LDS (512 thr x 4 x 16B), linear dest
#define STAGE(qd)                                                                             \
  {                                                                                           \
    const unsigned int* src_ = (const unsigned int*)wfrag + (qd) * 8192;                      \
    _Pragma("unroll")                                                                         \
    for (int i = 0; i < 4; ++i) {                                                             \
      __builtin_amdgcn_global_load_lds(                                                       \
          (const __attribute__((address_space(1))) unsigned int*)(src_ + (i * 512 + tid) * 4),\
          (__attribute__((address_space(3))) unsigned int*)&ldsw[(i * 512 + wave * 64) * 8],  \
          16, 0, 0);                                                                          \
    }                                                                                         \
  }

#define ALOAD(dst, c)                                  \
  {                                                    \
    dst[0] = *(const float4*)(xp + (c) * 32);          \
    dst[1] = *(const float4*)(xp + (c) * 32 + 4);      \
  }

  f32x4 acc[8];
#pragma unroll
  for (int t = 0; t < 8; ++t) acc[t] = (f32x4){0.f, 0.f, 0.f, 0.f};
  float4 avbuf[2][2];

  STAGE(0);
  ALOAD(avbuf[0], 0);
  ALOAD(avbuf[1], 1);
  __syncthreads(); // stage-0 + first x loads landed

#pragma unroll
  for (int qd = 0; qd < 4; ++qd) {
#pragma unroll
    for (int cc = 0; cc < 4; ++cc) {
      const int c = qd * 4 + cc;
      bf16x8 af = cvt8(avbuf[c & 1][0], avbuf[c & 1][1]);
      if (c < 14) ALOAD(avbuf[c & 1], c + 2); // keep 2 chunks of x in flight
#pragma unroll
      for (int t = 0; t < 8; ++t) {
        bf16x8 bfr = *(const bf16x8*)&ldsw[((cc * 8 + t) * 64 + lane) * 8];
        acc[t] = __builtin_amdgcn_mfma_f32_16x16x32_bf16(af, bfr, acc[t], 0, 0, 0);
      }
    }
    if (qd < 3) {
      __syncthreads(); // all waves done reading quarter qd
      STAGE(qd + 1);
      __syncthreads(); // quarter qd+1 landed
    }
  }
#undef STAGE
#undef ALOAD

  // epilogue: tanh + dot W2 + 16-lane reduce; D layout col=lane&15(+16t), row=(lane>>4)*4+r
  float w2v[8];
#pragma unroll
  for (int t = 0; t < 8; ++t) w2v[t] = W2[t * 16 + (lane & 15)];
  const int bfl = flag[0];
  float asum[4] = {0.f, 0.f, 0.f, 0.f};
#pragma unroll
  for (int t = 0; t < 8; ++t) {
#pragma unroll
    for (int r = 0; r < 4; ++r) {
      float h = 1.f - 2.f / (__expf(2.f * acc[t][r]) + 1.f); // tanh
      asum[r] += h * w2v[t];
    }
  }
#pragma unroll
  for (int m = 1; m < 16; m <<= 1) {
#pragma unroll
    for (int r = 0; r < 4; ++r) asum[r] += __shfl_xor(asum[r], m, 64);
  }
  if ((lane & 15) == 0) {
#pragma unroll
    for (int r = 0; r < 4; ++r) {
      int lr = wave * 16 + (lane >> 4) * 4 + r; // local row in block
      int row = blockIdx.x * 128 + lr;
      wt_l[lr] = __expf(asum[r]); // unnormalized softmax weight (|A|<=~9, safe)
      qq_l[lr] = is_pad(pad, bfl, row) ? 16 : ids[row];
    }
  }
  __syncthreads();

  // wave 0: deterministic grouping of the 128 rows by q
  if (wave == 0) {
    int q0 = qq_l[lane], q1 = qq_l[64 + lane];
    unsigned long long below = (1ull << lane) - 1ull;
    int pos = 0;
    for (int q = 0; q < 16; ++q) {
      if (lane == 0) off_l[q] = pos;
      unsigned long long m0 = __ballot(q0 == q);
      if (q0 == q) idx_l[pos + __popcll(m0 & below)] = lane;
      int c0 = __popcll(m0);
      unsigned long long m1 = __ballot(q1 == q);
      if (q1 == q) idx_l[pos + c0 + __popcll(m1 & below)] = 64 + lane;
      pos += c0 + __popcll(m1);
    }
    if (lane == 0) off_l[16] = pos;
  }
  __syncthreads();

  // per-block per-q weight sums (16 threads, fixed order -> deterministic)
  if (tid < 16) {
    float s = 0.f;
    for (int e = off_l[tid]; e < off_l[tid + 1]; ++e) s += wt_l[idx_l[e]];
    wsum_p[blockIdx.x * 16 + tid] = s;
  }

  // accumulation: wave owns cols [wave*64, wave*64+64); x rows are L2-hot (just read)
  const float* xc = x + (size_t)(blockIdx.x * 128) * LDIM + (wave * 64 + lane);
  float* pb = partial + ((size_t)blockIdx.x * 16) * 512 + (wave * 64 + lane);
#pragma unroll
  for (int q = 0; q < 16; ++q) {
    int e0 = off_l[q], e1 = off_l[q + 1];
    float a = 0.f;
    for (int e = e0; e < e1; ++e) {
      int r = idx_l[e];
      a = fmaf(wt_l[r], xc[(size_t)r * LDIM], a);
    }
    pb[(size_t)q * 512] = a;
  }
}

// ---------------- k4: reduce 64 block-partials per (b,q), normalize ----------------
__global__ __launch_bounds__(512) void k4_reduce(const float* __restrict__ partial,
                                                 const float* __restrict__ wsum_p,
                                                 float* __restrict__ out) {
  int b = blockIdx.x >> 4, q = blockIdx.x & 15;
  int tid = threadIdx.x;
  __shared__ float wsh;
  if (tid < 64) {
    float v = wsum_p[(b * 64 + tid) * 16 + q];
#pragma unroll
    for (int m = 1; m < 64; m <<= 1) v += __shfl_xor(v, m, 64);
    if (tid == 0) wsh = v;
  }
  __syncthreads();
  float ws = wsh;
  const float* pp = partial + ((size_t)(b * 64) * 16 + q) * 512 + tid;
  float ps = 0.f;
#pragma unroll 4
  for (int t = 0; t < 64; ++t) ps += pp[(size_t)t * 16 * 512];
  out[blockIdx.x * 512 + tid] = (ws > 0.f) ? (ps / ws) : 0.f;
}

extern "C" void kernel_launch(void* const* d_in, const int* in_sizes, int n_in,
                              void* d_out, int out_size, void* d_ws, size_t ws_size,
                              hipStream_t stream) {
  const float* x = (const float*)d_in[0];
  const float* W1 = (const float*)d_in[1];
  const float* W2 = (const float*)d_in[2];
  const int* ids = (const int*)d_in[3];
  const void* pad = d_in[4]; // bool ABI detected at runtime
  float* out = (float*)d_out;

  char* ws = (char*)d_ws;
  short* wfrag = (short*)ws;                      // 131072 B
  int* flag = (int*)(ws + 131072);                // 4 B
  float* wsum_p = (float*)(ws + 131200);          // 512*16*4 = 32768 B
  float* partial = (float*)(ws + 262144);         // 512*16*512*4 = 16 MB

  hipLaunchKernelGGL(k0_wfrag, dim3(32), dim3(256), 0, stream,
                     W1, wfrag, (const unsigned int*)pad, flag);
  hipLaunchKernelGGL(k1_fused, dim3((BATCH * NTOK) / 128), dim3(512), 0, stream,
                     x, wfrag, W2, ids, pad, flag, partial, wsum_p);
  hipLaunchKernelGGL(k4_reduce, dim3(BATCH * NQ), dim3(512), 0, stream,
                     partial, wsum_p, out);
}

// Round 7
// 66.577 us; speedup vs baseline: 1.3804x; 1.3804x over previous
//
#include <hip/hip_runtime.h>
#include <hip/hip_bf16.h>
#include <cstdint>
#include <cstddef>

typedef __attribute__((ext_vector_type(8))) short bf16x8;
typedef __attribute__((ext_vector_type(4))) float f32x4;

#define BATCH 8
#define NTOK 8192
#define LDIM 512
#define DDIM 128
#define NQ 16
#define NSEG 8
#define SEGLEN (NTOK / NSEG) /* 1024 */

static __device__ __forceinline__ short f2bf(float f) {
  uint32_t u = __float_as_uint(f);
  uint32_t r = u + 0x7fffu + ((u >> 16) & 1u); // RNE
  return (short)(r >> 16);
}

static __device__ __forceinline__ bf16x8 cvt8(float4 a, float4 b) {
  bf16x8 o;
  o[0] = f2bf(a.x); o[1] = f2bf(a.y); o[2] = f2bf(a.z); o[3] = f2bf(a.w);
  o[4] = f2bf(b.x); o[5] = f2bf(b.y); o[6] = f2bf(b.z); o[7] = f2bf(b.w);
  return o;
}

// pad-mask accessor robust to bool-ABI (byteFlag=1: 1B/elem, 0: int32/elem)
static __device__ __forceinline__ bool is_pad(const void* pad, int byteFlag, int j) {
  return byteFlag ? (((const unsigned char*)pad)[j] != 0)
                  : (((const int*)pad)[j] != 0);
}

// ---------------- k0: repack W1 -> MFMA B-frag order bf16; block 0 detects bool ABI ----------
// wfrag[(c*8 + t)*64 + lane][i] = bf16( W1[c*32 + (lane>>4)*8 + i][t*16 + (lane&15)] )
__global__ __launch_bounds__(256) void k0_wfrag(const float* __restrict__ W1,
                                                short* __restrict__ wfrag,
                                                const unsigned int* __restrict__ pad_raw,
                                                int* __restrict__ flag) {
  int tid = blockIdx.x * blockDim.x + threadIdx.x;
  if (tid < 16 * 8 * 64) {
    int l = tid & 63;
    int t = (tid >> 6) & 7;
    int c = tid >> 9;
    int kbase = c * 32 + (l >> 4) * 8;
    int col = t * 16 + (l & 15);
    bf16x8 frag;
#pragma unroll
    for (int i = 0; i < 8; ++i) frag[i] = f2bf(W1[(size_t)(kbase + i) * DDIM + col]);
    ((bf16x8*)wfrag)[tid] = frag;
  }
  if (blockIdx.x == 0) {
    int any_gt1 = 0;
    for (int i = threadIdx.x; i < 16384; i += 256)
      if (pad_raw[i] > 1u) any_gt1 = 1;
    unsigned long long m = __ballot(any_gt1);
    __shared__ int s[4];
    if ((threadIdx.x & 63) == 0) s[threadIdx.x >> 6] = (m != 0ull) ? 1 : 0;
    __syncthreads();
    if (threadIdx.x == 0) flag[0] = (s[0] | s[1] | s[2] | s[3]);
  }
}

// ---------------- k1: expw[row] = exp( tanh(x[row]W1)·W2 )  (no max needed: |A|<=~9) --------
// 512 thr (8 waves) x 16 rows/wave = 128 rows/block; grid 512; W1 in 4x32KB LDS quarters;
// x register-prefetched 4 chunks deep.
__global__ __launch_bounds__(512, 6) void k1_scores(const float* __restrict__ x,
                                                    const short* __restrict__ wfrag,
                                                    const float* __restrict__ W2,
                                                    float* __restrict__ expw) {
  __shared__ short ldsw[16384]; // 32 KB: one quarter of wfrag (4 K-chunks)
  const int tid = threadIdx.x, wave = tid >> 6, lane = tid & 63;
  const int rowBase = blockIdx.x * 128 + wave * 16;
  const float* xp = x + (size_t)(rowBase + (lane & 15)) * LDIM + ((lane >> 4) * 8);

// stage 32KB quarter qd of wfrag into LDS (512 thr x 4 x 16B), linear dest
#define STAGE(qd)                                                                             \
  {                                                                                           \
    const unsigned int* src_ = (const unsigned int*)wfrag + (qd) * 8192;                      \
    _Pragma("unroll")                                                                         \
    for (int i = 0; i < 4; ++i) {                                                             \
      __builtin_amdgcn_global_load_lds(                                                       \
          (const __attribute__((address_space(1))) unsigned int*)(src_ + (i * 512 + tid) * 4),\
          (__attribute__((address_space(3))) unsigned int*)&ldsw[(i * 512 + wave * 64) * 8],  \
          16, 0, 0);                                                                          \
    }                                                                                         \
  }

#define ALOAD(dst, c)                                  \
  {                                                    \
    dst[0] = *(const float4*)(xp + (c) * 32);          \
    dst[1] = *(const float4*)(xp + (c) * 32 + 4);      \
  }

  f32x4 acc[8];
#pragma unroll
  for (int t = 0; t < 8; ++t) acc[t] = (f32x4){0.f, 0.f, 0.f, 0.f};
  float4 avbuf[4][2]; // 4 chunks of x in flight

  STAGE(0);
  ALOAD(avbuf[0], 0);
  ALOAD(avbuf[1], 1);
  ALOAD(avbuf[2], 2);
  ALOAD(avbuf[3], 3);
  __syncthreads(); // stage-0 landed

#pragma unroll
  for (int qd = 0; qd < 4; ++qd) {
#pragma unroll
    for (int cc = 0; cc < 4; ++cc) {
      const int c = qd * 4 + cc;
      bf16x8 af = cvt8(avbuf[c & 3][0], avbuf[c & 3][1]);
      if (c < 12) ALOAD(avbuf[c & 3], c + 4); // keep 4 chunks of x in flight
#pragma unroll
      for (int t = 0; t < 8; ++t) {
        bf16x8 bfr = *(const bf16x8*)&ldsw[((cc * 8 + t) * 64 + lane) * 8];
        acc[t] = __builtin_amdgcn_mfma_f32_16x16x32_bf16(af, bfr, acc[t], 0, 0, 0);
      }
    }
    if (qd < 3) {
      __syncthreads(); // all waves done reading quarter qd
      STAGE(qd + 1);
      __syncthreads(); // quarter qd+1 landed
    }
  }
#undef STAGE
#undef ALOAD

  // epilogue: tanh + dot W2 + 16-lane reduce; D layout col=lane&15(+16t), row=(lane>>4)*4+r
  float w2v[8];
#pragma unroll
  for (int t = 0; t < 8; ++t) w2v[t] = W2[t * 16 + (lane & 15)];
  float asum[4] = {0.f, 0.f, 0.f, 0.f};
#pragma unroll
  for (int t = 0; t < 8; ++t) {
#pragma unroll
    for (int r = 0; r < 4; ++r) {
      float h = 1.f - 2.f / (__expf(2.f * acc[t][r]) + 1.f); // tanh
      asum[r] += h * w2v[t];
    }
  }
#pragma unroll
  for (int m = 1; m < 16; m <<= 1) {
#pragma unroll
    for (int r = 0; r < 4; ++r) asum[r] += __shfl_xor(asum[r], m, 64);
  }
  if ((lane & 15) == 0) {
    int rb = rowBase + (lane >> 4) * 4;
#pragma unroll
    for (int r = 0; r < 4; ++r) expw[rb + r] = __expf(asum[r]); // unnormalized weight
  }
}

// ---------------- k3: pooling partials; 8-wave compaction + 4 groups x 128 float4-threads ----
// grid ((b*16+q)*8+s) = 1024 blocks x 512 thr.
__global__ __launch_bounds__(512) void k3_pool(const float* __restrict__ x,
                                               const float* __restrict__ expw,
                                               const int* __restrict__ ids,
                                               const void* __restrict__ pad,
                                               const int* __restrict__ flag,
                                               float* __restrict__ partial,
                                               float* __restrict__ wsum) {
  int blk = blockIdx.x;
  int s = blk & 7, q = (blk >> 3) & 15, b = blk >> 7;
  int wave = threadIdx.x >> 6, lane = threadIdx.x & 63;
  int bfl = flag[0];
  __shared__ float w_u[1024];
  __shared__ unsigned short j_u[1024];
  __shared__ int cnt[8];
  __shared__ float wred[8];

  const int base = b * NTOK;
  const int tokBase = s * SEGLEN + wave * 128;

  // pass 1: per-wave member counts (2 rounds of 64)
  int myCnt = 0;
#pragma unroll
  for (int g = 0; g < 2; ++g) {
    int j = tokBase + g * 64 + lane;
    bool mem = (ids[base + j] == q) && !is_pad(pad, bfl, base + j);
    myCnt += __popcll(__ballot(mem));
  }
  if (lane == 0) cnt[wave] = myCnt;
  __syncthreads();

  int wpos = 0;
#pragma unroll
  for (int w = 0; w < 8; ++w) if (w < wave) wpos += cnt[w];
  const int total = cnt[0] + cnt[1] + cnt[2] + cnt[3] + cnt[4] + cnt[5] + cnt[6] + cnt[7];

  // pass 2: compact (token idx, weight) into unified list
  float wacc = 0.f;
#pragma unroll
  for (int g = 0; g < 2; ++g) {
    int j = tokBase + g * 64 + lane;
    bool mem = (ids[base + j] == q) && !is_pad(pad, bfl, base + j);
    float wt = mem ? expw[base + j] : 0.f;
    wacc += wt;
    unsigned long long mask = __ballot(mem);
    if (mem) {
      int pos = wpos + __popcll(mask & ((1ull << lane) - 1ull));
      w_u[pos] = wt;
      j_u[pos] = (unsigned short)j;
    }
    wpos += __popcll(mask);
  }
#pragma unroll
  for (int m = 1; m < 64; m <<= 1) wacc += __shfl_xor(wacc, m, 64);
  if (lane == 0) wred[wave] = wacc;
  __syncthreads();

  // accumulate: group grp walks its quarter of entries; 128 threads x float4 = 512 cols
  int grp = threadIdx.x >> 7, ct = threadIdx.x & 127;
  int c0 = ct * 4;
  int per = (total + 3) >> 2;
  int e0 = grp * per;
  int e1 = e0 + per; if (e1 > total) e1 = total;
  float4 av = {0.f, 0.f, 0.f, 0.f};
  if (e0 < e1) {
    float4 cur = *(const float4*)(x + (size_t)(base + j_u[e0]) * LDIM + c0);
    int e = e0;
    for (; e + 1 < e1; ++e) {
      float4 nxt = *(const float4*)(x + (size_t)(base + j_u[e + 1]) * LDIM + c0); // load-ahead
      float wt = w_u[e];
      av.x = fmaf(wt, cur.x, av.x); av.y = fmaf(wt, cur.y, av.y);
      av.z = fmaf(wt, cur.z, av.z); av.w = fmaf(wt, cur.w, av.w);
      cur = nxt;
    }
    float wt = w_u[e];
    av.x = fmaf(wt, cur.x, av.x); av.y = fmaf(wt, cur.y, av.y);
    av.z = fmaf(wt, cur.z, av.z); av.w = fmaf(wt, cur.w, av.w);
  }
  *(float4*)(partial + ((size_t)(blk * 4 + grp)) * LDIM + c0) = av;
  if (threadIdx.x == 0)
    wsum[blk] = wred[0] + wred[1] + wred[2] + wred[3] + wred[4] + wred[5] + wred[6] + wred[7];
}

// ---------------- k4: combine 32 partial slots per (b,q) + normalize ----------------
__global__ __launch_bounds__(512) void k4_reduce(const float* __restrict__ partial,
                                                 const float* __restrict__ wsum,
                                                 float* __restrict__ out) {
  int bq = blockIdx.x; // b*16+q
  int b = bq >> 4, q = bq & 15;
  int c = threadIdx.x;
  float ws = 0.f;
#pragma unroll
  for (int s = 0; s < 8; ++s) ws += wsum[b * 128 + q * 8 + s];
  float ps = 0.f;
#pragma unroll
  for (int s = 0; s < 8; ++s)
#pragma unroll
    for (int g = 0; g < 4; ++g)
      ps += partial[((size_t)((b * 128 + q * 8 + s) * 4 + g)) * LDIM + c];
  out[bq * 512 + c] = (ws > 0.f) ? (ps / ws) : 0.f;
}

extern "C" void kernel_launch(void* const* d_in, const int* in_sizes, int n_in,
                              void* d_out, int out_size, void* d_ws, size_t ws_size,
                              hipStream_t stream) {
  const float* x = (const float*)d_in[0];
  const float* W1 = (const float*)d_in[1];
  const float* W2 = (const float*)d_in[2];
  const int* ids = (const int*)d_in[3];
  const void* pad = d_in[4]; // bool ABI detected at runtime
  float* out = (float*)d_out;

  char* ws = (char*)d_ws;
  short* wfrag = (short*)ws;                 // 131072 B
  int* flag = (int*)(ws + 131072);           // 4 B
  float* expw = (float*)(ws + 131200);       // 262144 B
  float* wsum = (float*)(ws + 393344);       // 4096 B
  float* partial = (float*)(ws + 397440);    // 1024*4*512*4 = 8388608 B

  hipLaunchKernelGGL(k0_wfrag, dim3(32), dim3(256), 0, stream,
                     W1, wfrag, (const unsigned int*)pad, flag);
  hipLaunchKernelGGL(k1_scores, dim3((BATCH * NTOK) / 128), dim3(512), 0, stream,
                     x, wfrag, W2, expw);
  hipLaunchKernelGGL(k3_pool, dim3(BATCH * NQ * NSEG), dim3(512), 0, stream,
                     x, expw, ids, pad, flag, partial, wsum);
  hipLaunchKernelGGL(k4_reduce, dim3(BATCH * NQ), dim3(512), 0, stream,
                     partial, wsum, out);
}